// Round 1
// baseline (551.107 us; speedup 1.0000x reference)
//
#include <hip/hip_runtime.h>

// Problem constants (match reference)
constexpr int NP = 65536;   // N query points
constexpr int JJ = 24;      // J
constexpr int CC = 8;       // C
constexpr int PP = 8;       // P (pose dim)
constexpr int LL = 128;     // L (plane resolution)
constexpr int OUTC = 3 * CC;           // 24 output channels
constexpr int TOTAL = NP * OUTC;       // 1,572,864 output elems

// ---------------- mean reduction (deterministic, 2-stage) ----------------

__global__ __launch_bounds__(256) void k_partial(const float* __restrict__ qp,
                                                 float* __restrict__ partial) {
    __shared__ float s[3][256];
    int t = threadIdx.x;
    int n = blockIdx.x * 256 + t;       // grid = 256 blocks -> covers 65536 exactly
    s[0][t] = qp[n * 3 + 0];
    s[1][t] = qp[n * 3 + 1];
    s[2][t] = qp[n * 3 + 2];
    __syncthreads();
    for (int off = 128; off > 0; off >>= 1) {
        if (t < off) {
            s[0][t] += s[0][t + off];
            s[1][t] += s[1][t + off];
            s[2][t] += s[2][t + off];
        }
        __syncthreads();
    }
    if (t == 0) {
        partial[blockIdx.x * 4 + 0] = s[0][0];
        partial[blockIdx.x * 4 + 1] = s[1][0];
        partial[blockIdx.x * 4 + 2] = s[2][0];
    }
}

__global__ __launch_bounds__(256) void k_final(const float* __restrict__ partial,
                                               float* __restrict__ mean) {
    __shared__ float s[3][256];
    int t = threadIdx.x;
    s[0][t] = partial[t * 4 + 0];
    s[1][t] = partial[t * 4 + 1];
    s[2][t] = partial[t * 4 + 2];
    __syncthreads();
    for (int off = 128; off > 0; off >>= 1) {
        if (t < off) {
            s[0][t] += s[0][t + off];
            s[1][t] += s[1][t + off];
            s[2][t] += s[2][t + off];
        }
        __syncthreads();
    }
    if (t < 3) mean[t] = s[t][0] * (1.0f / 65536.0f);
}

// ---------------- main fused sample + einsum kernel ----------------
// One thread per output element (n', c'). c' = 24 channels: [0,8)=plane x,
// [8,16)=plane y, [16,24)=plane z. For each j: flat i = n'*192 + j*8 + c
// decodes jc = i>>16 (sampled channel) and n = i&65535 (sampled point),
// replicating the reference's raw reshape of the (1, J*C, N, 1) tensor.
__global__ __launch_bounds__(256) void k_main(
    const float* __restrict__ featx, const float* __restrict__ featy,
    const float* __restrict__ featz, const float* __restrict__ qp,
    const float* __restrict__ scale, const float* __restrict__ sw,
    const int* __restrict__ idp, const float* __restrict__ mean,
    float* __restrict__ out) {
    int t = blockIdx.x * 256 + threadIdx.x;
    if (t >= TOTAL) return;
    int np = t / OUTC;          // n'
    int cp = t - np * OUTC;     // c' in [0,24)
    int p  = cp >> 3;           // plane 0,1,2
    int c  = cp & 7;            // channel within plane

    const float* feat = (p == 0) ? featx : (p == 1) ? featy : featz;
    int pid = *idp;

    // coordinate mapping: width coord from component (p+1)%3, height from p
    int wc = (p + 1) - ((p + 1) >= 3 ? 3 : 0);   // (p+1)%3
    int hc = p;
    float mw = mean[wc], mh = mean[hc];
    float invw = 2.0f / scale[wc];
    float invh = 2.0f / scale[hc];

    const float* featpid = feat + (size_t)pid * (LL * LL * CC);
    int ibase = np * 192 + c;
    float acc = 0.0f;

#pragma unroll 4
    for (int j = 0; j < JJ; ++j) {
        int i  = ibase + j * 8;
        int jc = i >> 16;
        int n  = i & 65535;
        int jimg = jc >> 3;
        int cimg = jc & 7;
        const float* img = featpid + (size_t)jimg * (PP * LL * LL * CC) + cimg;

        float gw = (qp[n * 3 + wc] - mw) * invw;   // in ~[-1,1]
        float gh = (qp[n * 3 + hc] - mh) * invh;
        float ixf = (gw + 1.0f) * 63.5f;           // (g+1)*0.5*(L-1)
        float iyf = (gh + 1.0f) * 63.5f;
        float ix0 = floorf(ixf);
        float iy0 = floorf(iyf);
        float fx = ixf - ix0;
        float fy = iyf - iy0;
        int x0i = (int)ix0;
        int y0i = (int)iy0;
        int x0 = min(127, max(0, x0i));
        int x1 = min(127, max(0, x0i + 1));
        int y0 = min(127, max(0, y0i));
        int y1 = min(127, max(0, y0i + 1));

        int r0 = y0 * (LL * CC);
        int r1 = y1 * (LL * CC);
        float v00 = img[r0 + x0 * CC];
        float v01 = img[r0 + x1 * CC];
        float v10 = img[r1 + x0 * CC];
        float v11 = img[r1 + x1 * CC];

        float omfx = 1.0f - fx;
        float omfy = 1.0f - fy;
        float S = omfx * omfy * v00 + fx * omfy * v01 +
                  omfx * fy * v10 + fx * fy * v11;
        acc += sw[np * JJ + j] * S;
    }
    out[t] = acc;
}

extern "C" void kernel_launch(void* const* d_in, const int* in_sizes, int n_in,
                              void* d_out, int out_size, void* d_ws, size_t ws_size,
                              hipStream_t stream) {
    const float* featx = (const float*)d_in[0];
    const float* featy = (const float*)d_in[1];
    const float* featz = (const float*)d_in[2];
    const float* qp    = (const float*)d_in[3];
    const float* scale = (const float*)d_in[4];
    const float* sw    = (const float*)d_in[5];
    const int*   idp   = (const int*)d_in[6];
    float* out = (float*)d_out;

    float* ws = (float*)d_ws;
    float* mean    = ws;        // 4 floats
    float* partial = ws + 4;    // 256 * 4 floats

    k_partial<<<256, 256, 0, stream>>>(qp, partial);
    k_final<<<1, 256, 0, stream>>>(partial, mean);
    k_main<<<(TOTAL + 255) / 256, 256, 0, stream>>>(
        featx, featy, featz, qp, scale, sw, idp, mean, out);
}

// Round 2
// 136.084 us; speedup vs baseline: 4.0498x; 4.0498x over previous
//
#include <hip/hip_runtime.h>

// Problem constants (match reference)
constexpr int NP = 65536;   // N query points
constexpr int JJ = 24;      // J
constexpr int CC = 8;       // C
constexpr int PP = 8;       // P (pose dim)
constexpr int LL = 128;     // L (plane resolution)
constexpr int OUTC = 3 * CC;           // 24 output channels
constexpr int TOTAL = NP * OUTC;       // 1,572,864 output elems
constexpr size_t TPL = (size_t)192 * 65536;   // T elems per plane (12.58M)
constexpr size_t TSZ = 3 * TPL;               // 37.7M floats = 151 MB

// ---------------- mean reduction (deterministic, 2-stage) ----------------

__global__ __launch_bounds__(256) void k_partial(const float* __restrict__ qp,
                                                 float* __restrict__ partial) {
    __shared__ float s[3][256];
    int t = threadIdx.x;
    int n = blockIdx.x * 256 + t;
    s[0][t] = qp[n * 3 + 0];
    s[1][t] = qp[n * 3 + 1];
    s[2][t] = qp[n * 3 + 2];
    __syncthreads();
    for (int off = 128; off > 0; off >>= 1) {
        if (t < off) {
            s[0][t] += s[0][t + off];
            s[1][t] += s[1][t + off];
            s[2][t] += s[2][t + off];
        }
        __syncthreads();
    }
    if (t == 0) {
        partial[blockIdx.x * 4 + 0] = s[0][0];
        partial[blockIdx.x * 4 + 1] = s[1][0];
        partial[blockIdx.x * 4 + 2] = s[2][0];
    }
}

__global__ __launch_bounds__(256) void k_final(const float* __restrict__ partial,
                                               float* __restrict__ mean) {
    __shared__ float s[3][256];
    int t = threadIdx.x;
    s[0][t] = partial[t * 4 + 0];
    s[1][t] = partial[t * 4 + 1];
    s[2][t] = partial[t * 4 + 2];
    __syncthreads();
    for (int off = 128; off > 0; off >>= 1) {
        if (t < off) {
            s[0][t] += s[0][t + off];
            s[1][t] += s[1][t + off];
            s[2][t] += s[2][t + off];
        }
        __syncthreads();
    }
    if (t < 3) mean[t] = s[t][0] * (1.0f / 65536.0f);
}

// ---------------- stage 1: vectorized bilinear sampling ----------------
// Thread = (plane p, image jimg, point n). All 8 channels jc = jimg*8+c'
// sample the SAME (x,y) -> 4 taps x 2 float4 loads. Block = 256 consecutive
// n of ONE image; chunked XCD swizzle keeps each XCD on ~1 image at a time
// (524 KB, L2-resident). Writes T[p][(jc<<16)|n] -> 8 coalesced streams.
__global__ __launch_bounds__(256) void k_sample(
    const float* __restrict__ featx, const float* __restrict__ featy,
    const float* __restrict__ featz, const float* __restrict__ qp,
    const float* __restrict__ scale, const int* __restrict__ idp,
    const float* __restrict__ mean, float* __restrict__ T) {
    // grid = 72 groups * 256 chunks = 18432 blocks; 18432/8 = 2304 per XCD
    int b = blockIdx.x;
    int Lid = (b & 7) * 2304 + (b >> 3);   // logical work id, chunked per XCD
    int group = Lid >> 8;                  // 0..71 = p*24 + jimg
    int chunk = Lid & 255;
    int p = group / 24;
    int jimg = group - p * 24;
    int n = chunk * 256 + threadIdx.x;

    const float* feat = (p == 0) ? featx : (p == 1) ? featy : featz;
    int pid = *idp;
    const float* img = feat + ((size_t)jimg * PP + (size_t)pid) * (LL * LL * CC);

    int wc = (p + 1) - ((p + 1) >= 3 ? 3 : 0);   // (p+1)%3
    int hc = p;
    float mw = mean[wc], mh = mean[hc];
    float invw = 2.0f / scale[wc];
    float invh = 2.0f / scale[hc];

    float gw = (qp[n * 3 + wc] - mw) * invw;
    float gh = (qp[n * 3 + hc] - mh) * invh;
    float ixf = (gw + 1.0f) * 63.5f;
    float iyf = (gh + 1.0f) * 63.5f;
    float ix0 = floorf(ixf);
    float iy0 = floorf(iyf);
    float fx = ixf - ix0;
    float fy = iyf - iy0;
    int x0i = (int)ix0;
    int y0i = (int)iy0;
    int x0 = min(127, max(0, x0i));
    int x1 = min(127, max(0, x0i + 1));
    int y0 = min(127, max(0, y0i));
    int y1 = min(127, max(0, y0i + 1));

    const float4* t00 = (const float4*)(img + ((size_t)(y0 * LL + x0)) * CC);
    const float4* t01 = (const float4*)(img + ((size_t)(y0 * LL + x1)) * CC);
    const float4* t10 = (const float4*)(img + ((size_t)(y1 * LL + x0)) * CC);
    const float4* t11 = (const float4*)(img + ((size_t)(y1 * LL + x1)) * CC);
    float4 a0 = t00[0], a1 = t00[1];
    float4 b0 = t01[0], b1 = t01[1];
    float4 c0 = t10[0], c1 = t10[1];
    float4 d0 = t11[0], d1 = t11[1];

    float omfx = 1.0f - fx;
    float omfy = 1.0f - fy;
    float w00 = omfx * omfy, w01 = fx * omfy, w10 = omfx * fy, w11 = fx * fy;

    float v[8];
    v[0] = w00 * a0.x + w01 * b0.x + w10 * c0.x + w11 * d0.x;
    v[1] = w00 * a0.y + w01 * b0.y + w10 * c0.y + w11 * d0.y;
    v[2] = w00 * a0.z + w01 * b0.z + w10 * c0.z + w11 * d0.z;
    v[3] = w00 * a0.w + w01 * b0.w + w10 * c0.w + w11 * d0.w;
    v[4] = w00 * a1.x + w01 * b1.x + w10 * c1.x + w11 * d1.x;
    v[5] = w00 * a1.y + w01 * b1.y + w10 * c1.y + w11 * d1.y;
    v[6] = w00 * a1.z + w01 * b1.z + w10 * c1.z + w11 * d1.z;
    v[7] = w00 * a1.w + w01 * b1.w + w10 * c1.w + w11 * d1.w;

    size_t base = (size_t)p * TPL + ((size_t)(jimg * 8) << 16) + (size_t)n;
#pragma unroll
    for (int cp = 0; cp < 8; ++cp) {
        T[base + ((size_t)cp << 16)] = v[cp];
    }
}

// ---------------- stage 2: coalesced weighted reduction ----------------
// T[p][i] at i = np*192 + j*8 + c is exactly the sample output (np,j,c)
// needs (the reshape-scramble is the identity on the flat index).
__global__ __launch_bounds__(256) void k_combine(
    const float* __restrict__ T, const float* __restrict__ sw,
    float* __restrict__ out) {
    int t = blockIdx.x * 256 + threadIdx.x;   // [0, 3*65536)
    int p = t >> 16;
    int np = t & 65535;
    const float* Tp = T + (size_t)p * TPL + (size_t)np * 192;
    const float* swp = sw + (size_t)np * JJ;
    float acc[8] = {0, 0, 0, 0, 0, 0, 0, 0};
#pragma unroll
    for (int j = 0; j < JJ; ++j) {
        float w = swp[j];
        float4 u0 = *(const float4*)(Tp + j * 8);
        float4 u1 = *(const float4*)(Tp + j * 8 + 4);
        acc[0] += w * u0.x;
        acc[1] += w * u0.y;
        acc[2] += w * u0.z;
        acc[3] += w * u0.w;
        acc[4] += w * u1.x;
        acc[5] += w * u1.y;
        acc[6] += w * u1.z;
        acc[7] += w * u1.w;
    }
    float4* o = (float4*)(out + (size_t)np * OUTC + p * 8);
    o[0] = make_float4(acc[0], acc[1], acc[2], acc[3]);
    o[1] = make_float4(acc[4], acc[5], acc[6], acc[7]);
}

// ---------------- fallback (round-1 kernel) if ws too small ----------------
__global__ __launch_bounds__(256) void k_main(
    const float* __restrict__ featx, const float* __restrict__ featy,
    const float* __restrict__ featz, const float* __restrict__ qp,
    const float* __restrict__ scale, const float* __restrict__ sw,
    const int* __restrict__ idp, const float* __restrict__ mean,
    float* __restrict__ out) {
    int t = blockIdx.x * 256 + threadIdx.x;
    if (t >= TOTAL) return;
    int np = t / OUTC;
    int cp = t - np * OUTC;
    int p  = cp >> 3;
    int c  = cp & 7;

    const float* feat = (p == 0) ? featx : (p == 1) ? featy : featz;
    int pid = *idp;
    int wc = (p + 1) - ((p + 1) >= 3 ? 3 : 0);
    int hc = p;
    float mw = mean[wc], mh = mean[hc];
    float invw = 2.0f / scale[wc];
    float invh = 2.0f / scale[hc];

    const float* featpid = feat + (size_t)pid * (LL * LL * CC);
    int ibase = np * 192 + c;
    float acc = 0.0f;

#pragma unroll 4
    for (int j = 0; j < JJ; ++j) {
        int i  = ibase + j * 8;
        int jc = i >> 16;
        int n  = i & 65535;
        int jimg = jc >> 3;
        int cimg = jc & 7;
        const float* img = featpid + (size_t)jimg * (PP * LL * LL * CC) + cimg;

        float gw = (qp[n * 3 + wc] - mw) * invw;
        float gh = (qp[n * 3 + hc] - mh) * invh;
        float ixf = (gw + 1.0f) * 63.5f;
        float iyf = (gh + 1.0f) * 63.5f;
        float ix0 = floorf(ixf);
        float iy0 = floorf(iyf);
        float fx = ixf - ix0;
        float fy = iyf - iy0;
        int x0i = (int)ix0;
        int y0i = (int)iy0;
        int x0 = min(127, max(0, x0i));
        int x1 = min(127, max(0, x0i + 1));
        int y0 = min(127, max(0, y0i));
        int y1 = min(127, max(0, y0i + 1));

        int r0 = y0 * (LL * CC);
        int r1 = y1 * (LL * CC);
        float v00 = img[r0 + x0 * CC];
        float v01 = img[r0 + x1 * CC];
        float v10 = img[r1 + x0 * CC];
        float v11 = img[r1 + x1 * CC];

        float omfx = 1.0f - fx;
        float omfy = 1.0f - fy;
        float S = omfx * omfy * v00 + fx * omfy * v01 +
                  omfx * fy * v10 + fx * fy * v11;
        acc += sw[np * JJ + j] * S;
    }
    out[t] = acc;
}

extern "C" void kernel_launch(void* const* d_in, const int* in_sizes, int n_in,
                              void* d_out, int out_size, void* d_ws, size_t ws_size,
                              hipStream_t stream) {
    const float* featx = (const float*)d_in[0];
    const float* featy = (const float*)d_in[1];
    const float* featz = (const float*)d_in[2];
    const float* qp    = (const float*)d_in[3];
    const float* scale = (const float*)d_in[4];
    const float* sw    = (const float*)d_in[5];
    const int*   idp   = (const int*)d_in[6];
    float* out = (float*)d_out;

    float* ws = (float*)d_ws;
    size_t needed = (TSZ + 1024 + 4) * sizeof(float);

    if (ws_size >= needed) {
        float* T       = ws;                 // TSZ floats
        float* partial = ws + TSZ;           // 1024 floats
        float* mean    = ws + TSZ + 1024;    // 4 floats
        k_partial<<<256, 256, 0, stream>>>(qp, partial);
        k_final<<<1, 256, 0, stream>>>(partial, mean);
        k_sample<<<72 * 256, 256, 0, stream>>>(featx, featy, featz, qp, scale,
                                               idp, mean, T);
        k_combine<<<3 * 65536 / 256, 256, 0, stream>>>(T, sw, out);
    } else {
        float* mean    = ws;
        float* partial = ws + 4;
        k_partial<<<256, 256, 0, stream>>>(qp, partial);
        k_final<<<1, 256, 0, stream>>>(partial, mean);
        k_main<<<(TOTAL + 255) / 256, 256, 0, stream>>>(
            featx, featy, featz, qp, scale, sw, idp, mean, out);
    }
}

// Round 3
// 93.332 us; speedup vs baseline: 5.9048x; 1.4581x over previous
//
#include <hip/hip_runtime.h>

// Problem constants (match reference)
constexpr int NP = 65536;   // N query points
constexpr int JJ = 24;      // J
constexpr int CC = 8;       // C
constexpr int PP = 8;       // P (pose dim)
constexpr int LL = 128;     // L (plane resolution)
constexpr int OUTC = 3 * CC;              // 24 output channels
constexpr int TOTAL = NP * OUTC;          // 1,572,864 output elems
constexpr size_t TPL = (size_t)192 * 65536;   // T elems per plane
constexpr size_t TSZ = 3 * TPL;               // 37.7M halves = 75.5 MB

typedef _Float16 half8 __attribute__((ext_vector_type(8)));

// ---------------- mean reduction (deterministic, 2-stage) ----------------

__global__ __launch_bounds__(256) void k_partial(const float* __restrict__ qp,
                                                 float* __restrict__ partial) {
    __shared__ float s[3][256];
    int t = threadIdx.x;
    int n = blockIdx.x * 256 + t;
    s[0][t] = qp[n * 3 + 0];
    s[1][t] = qp[n * 3 + 1];
    s[2][t] = qp[n * 3 + 2];
    __syncthreads();
    for (int off = 128; off > 0; off >>= 1) {
        if (t < off) {
            s[0][t] += s[0][t + off];
            s[1][t] += s[1][t + off];
            s[2][t] += s[2][t + off];
        }
        __syncthreads();
    }
    if (t == 0) {
        partial[blockIdx.x * 4 + 0] = s[0][0];
        partial[blockIdx.x * 4 + 1] = s[1][0];
        partial[blockIdx.x * 4 + 2] = s[2][0];
    }
}

__global__ __launch_bounds__(256) void k_final(const float* __restrict__ partial,
                                               float* __restrict__ mean) {
    __shared__ float s[3][256];
    int t = threadIdx.x;
    s[0][t] = partial[t * 4 + 0];
    s[1][t] = partial[t * 4 + 1];
    s[2][t] = partial[t * 4 + 2];
    __syncthreads();
    for (int off = 128; off > 0; off >>= 1) {
        if (t < off) {
            s[0][t] += s[0][t + off];
            s[1][t] += s[1][t + off];
            s[2][t] += s[2][t + off];
        }
        __syncthreads();
    }
    if (t < 3) mean[t] = s[t][0] * (1.0f / 65536.0f);
}

// ---------------- stage 1: pair-lane bilinear sampling, fp16 out ----------
// Two lanes per point: lane 2k loads the low float4 of each tap, lane 2k+1
// the high float4. Both halves of a tap sit in the SAME 64B line (texel =
// 32B aligned), so L1 merges the pair -> 4 line-lookups per point instead
// of 8. Block = 128 consecutive n of ONE image; chunked XCD swizzle keeps
// each XCD on ~1 image (524 KB, L2-resident). Writes fp16 T[(jc<<16)|n].
__global__ __launch_bounds__(256) void k_sample(
    const float* __restrict__ featx, const float* __restrict__ featy,
    const float* __restrict__ featz, const float* __restrict__ qp,
    const float* __restrict__ scale, const int* __restrict__ idp,
    const float* __restrict__ mean, _Float16* __restrict__ T) {
    // grid = 72 groups * 512 chunks = 36864 blocks; 36864/8 = 4608 per XCD
    int b = blockIdx.x;
    int Lid = (b & 7) * 4608 + (b >> 3);   // logical work id, chunked per XCD
    int group = Lid >> 9;                  // 0..71 = p*24 + jimg
    int chunk = Lid & 511;
    int p = group / 24;
    int jimg = group - p * 24;
    int n = (chunk << 7) + (threadIdx.x >> 1);
    int h = threadIdx.x & 1;               // which float4 half of each tap

    const float* feat = (p == 0) ? featx : (p == 1) ? featy : featz;
    int pid = *idp;
    const float* img = feat + ((size_t)jimg * PP + (size_t)pid) * (LL * LL * CC);

    int wc = (p + 1) - ((p + 1) >= 3 ? 3 : 0);   // (p+1)%3
    int hc = p;
    float mw = mean[wc], mh = mean[hc];
    float invw = 2.0f / scale[wc];
    float invh = 2.0f / scale[hc];

    float gw = (qp[n * 3 + wc] - mw) * invw;
    float gh = (qp[n * 3 + hc] - mh) * invh;
    float ixf = (gw + 1.0f) * 63.5f;
    float iyf = (gh + 1.0f) * 63.5f;
    float ix0 = floorf(ixf);
    float iy0 = floorf(iyf);
    float fx = ixf - ix0;
    float fy = iyf - iy0;
    int x0i = (int)ix0;
    int y0i = (int)iy0;
    int x0 = min(127, max(0, x0i));
    int x1 = min(127, max(0, x0i + 1));
    int y0 = min(127, max(0, y0i));
    int y1 = min(127, max(0, y0i + 1));

    const float4* base4 = (const float4*)img;
    float4 a = base4[(y0 * LL + x0) * 2 + h];   // tap (x0,y0), my half
    float4 bq = base4[(y0 * LL + x1) * 2 + h];  // tap (x1,y0)
    float4 c = base4[(y1 * LL + x0) * 2 + h];   // tap (x0,y1)
    float4 d = base4[(y1 * LL + x1) * 2 + h];   // tap (x1,y1)

    float omfx = 1.0f - fx;
    float omfy = 1.0f - fy;
    float w00 = omfx * omfy, w01 = fx * omfy, w10 = omfx * fy, w11 = fx * fy;

    float v0 = w00 * a.x + w01 * bq.x + w10 * c.x + w11 * d.x;
    float v1 = w00 * a.y + w01 * bq.y + w10 * c.y + w11 * d.y;
    float v2 = w00 * a.z + w01 * bq.z + w10 * c.z + w11 * d.z;
    float v3 = w00 * a.w + w01 * bq.w + w10 * c.w + w11 * d.w;

    // channels jc = jimg*8 + h*4 + ci, flat index i = (jc<<16) | n
    size_t base = (size_t)p * TPL + ((size_t)(jimg * 8 + h * 4) << 16) + (size_t)n;
    T[base]                       = (_Float16)v0;
    T[base + ((size_t)1 << 16)]   = (_Float16)v1;
    T[base + ((size_t)2 << 16)]   = (_Float16)v2;
    T[base + ((size_t)3 << 16)]   = (_Float16)v3;
}

// ---------------- stage 2: coalesced weighted reduction (fp16 in) --------
// T[p][i] at i = np*192 + j*8 + c is exactly the sample the output (np,j,c)
// needs (the reshape-scramble is the identity on the flat index).
__global__ __launch_bounds__(256) void k_combine(
    const _Float16* __restrict__ T, const float* __restrict__ sw,
    float* __restrict__ out) {
    int t = blockIdx.x * 256 + threadIdx.x;   // [0, 3*65536)
    int p = t >> 16;
    int np = t & 65535;
    const _Float16* Tp = T + (size_t)p * TPL + (size_t)np * 192;
    const float* swp = sw + (size_t)np * JJ;

    float w[24];
#pragma unroll
    for (int q = 0; q < 6; ++q) {
        float4 wv = *(const float4*)(swp + q * 4);
        w[q * 4 + 0] = wv.x;
        w[q * 4 + 1] = wv.y;
        w[q * 4 + 2] = wv.z;
        w[q * 4 + 3] = wv.w;
    }

    float acc[8] = {0, 0, 0, 0, 0, 0, 0, 0};
#pragma unroll
    for (int j = 0; j < JJ; ++j) {
        half8 u = *(const half8*)(Tp + j * 8);
        float wj = w[j];
#pragma unroll
        for (int ci = 0; ci < 8; ++ci) acc[ci] += wj * (float)u[ci];
    }
    float4* o = (float4*)(out + (size_t)np * OUTC + p * 8);
    o[0] = make_float4(acc[0], acc[1], acc[2], acc[3]);
    o[1] = make_float4(acc[4], acc[5], acc[6], acc[7]);
}

// ---------------- fallback (round-1 kernel) if ws too small ----------------
__global__ __launch_bounds__(256) void k_main(
    const float* __restrict__ featx, const float* __restrict__ featy,
    const float* __restrict__ featz, const float* __restrict__ qp,
    const float* __restrict__ scale, const float* __restrict__ sw,
    const int* __restrict__ idp, const float* __restrict__ mean,
    float* __restrict__ out) {
    int t = blockIdx.x * 256 + threadIdx.x;
    if (t >= TOTAL) return;
    int np = t / OUTC;
    int cp = t - np * OUTC;
    int p  = cp >> 3;
    int c  = cp & 7;

    const float* feat = (p == 0) ? featx : (p == 1) ? featy : featz;
    int pid = *idp;
    int wc = (p + 1) - ((p + 1) >= 3 ? 3 : 0);
    int hc = p;
    float mw = mean[wc], mh = mean[hc];
    float invw = 2.0f / scale[wc];
    float invh = 2.0f / scale[hc];

    const float* featpid = feat + (size_t)pid * (LL * LL * CC);
    int ibase = np * 192 + c;
    float acc = 0.0f;

#pragma unroll 4
    for (int j = 0; j < JJ; ++j) {
        int i  = ibase + j * 8;
        int jc = i >> 16;
        int n  = i & 65535;
        int jimg = jc >> 3;
        int cimg = jc & 7;
        const float* img = featpid + (size_t)jimg * (PP * LL * LL * CC) + cimg;

        float gw = (qp[n * 3 + wc] - mw) * invw;
        float gh = (qp[n * 3 + hc] - mh) * invh;
        float ixf = (gw + 1.0f) * 63.5f;
        float iyf = (gh + 1.0f) * 63.5f;
        float ix0 = floorf(ixf);
        float iy0 = floorf(iyf);
        float fx = ixf - ix0;
        float fy = iyf - iy0;
        int x0i = (int)ix0;
        int y0i = (int)iy0;
        int x0 = min(127, max(0, x0i));
        int x1 = min(127, max(0, x0i + 1));
        int y0 = min(127, max(0, y0i));
        int y1 = min(127, max(0, y0i + 1));

        int r0 = y0 * (LL * CC);
        int r1 = y1 * (LL * CC);
        float v00 = img[r0 + x0 * CC];
        float v01 = img[r0 + x1 * CC];
        float v10 = img[r1 + x0 * CC];
        float v11 = img[r1 + x1 * CC];

        float omfx = 1.0f - fx;
        float omfy = 1.0f - fy;
        float S = omfx * omfy * v00 + fx * omfy * v01 +
                  omfx * fy * v10 + fx * fy * v11;
        acc += sw[np * JJ + j] * S;
    }
    out[t] = acc;
}

extern "C" void kernel_launch(void* const* d_in, const int* in_sizes, int n_in,
                              void* d_out, int out_size, void* d_ws, size_t ws_size,
                              hipStream_t stream) {
    const float* featx = (const float*)d_in[0];
    const float* featy = (const float*)d_in[1];
    const float* featz = (const float*)d_in[2];
    const float* qp    = (const float*)d_in[3];
    const float* scale = (const float*)d_in[4];
    const float* sw    = (const float*)d_in[5];
    const int*   idp   = (const int*)d_in[6];
    float* out = (float*)d_out;

    size_t needed = TSZ * sizeof(_Float16) + (1024 + 4) * sizeof(float);

    if (ws_size >= needed) {
        _Float16* T    = (_Float16*)d_ws;           // TSZ halves (75.5 MB)
        float* partial = (float*)(T + TSZ);         // 1024 floats
        float* mean    = partial + 1024;            // 4 floats
        k_partial<<<256, 256, 0, stream>>>(qp, partial);
        k_final<<<1, 256, 0, stream>>>(partial, mean);
        k_sample<<<72 * 512, 256, 0, stream>>>(featx, featy, featz, qp, scale,
                                               idp, mean, T);
        k_combine<<<3 * 65536 / 256, 256, 0, stream>>>(T, sw, out);
    } else {
        float* ws = (float*)d_ws;
        float* mean    = ws;
        float* partial = ws + 4;
        k_partial<<<256, 256, 0, stream>>>(qp, partial);
        k_final<<<1, 256, 0, stream>>>(partial, mean);
        k_main<<<(TOTAL + 255) / 256, 256, 0, stream>>>(
            featx, featy, featz, qp, scale, sw, idp, mean, out);
    }
}

// Round 4
// 89.578 us; speedup vs baseline: 6.1523x; 1.0419x over previous
//
#include <hip/hip_runtime.h>

// Problem constants (match reference)
constexpr int NP = 65536;   // N query points
constexpr int JJ = 24;      // J
constexpr int CC = 8;       // C
constexpr int PP = 8;       // P (pose dim)
constexpr int LL = 128;     // L (plane resolution)
constexpr int OUTC = 3 * CC;              // 24 output channels
constexpr int TOTAL = NP * OUTC;          // 1,572,864 output elems
constexpr size_t TPL = (size_t)192 * 65536;   // T elems per plane
constexpr size_t TSZ = 3 * TPL;               // 37.7M halves = 75.5 MB
constexpr size_t FSZ = (size_t)72 * 131072;   // fp16 feature table elems (18.9 MB)
constexpr size_t CSZ = (size_t)3 * 65536;     // coord table entries (uint2)

typedef _Float16 h8 __attribute__((ext_vector_type(8)));
typedef _Float16 h2 __attribute__((ext_vector_type(2)));

// ---------------- mean reduction (deterministic, 2-stage) ----------------

__global__ __launch_bounds__(256) void k_partial(const float* __restrict__ qp,
                                                 float* __restrict__ partial) {
    __shared__ float s[3][256];
    int t = threadIdx.x;
    int n = blockIdx.x * 256 + t;
    s[0][t] = qp[n * 3 + 0];
    s[1][t] = qp[n * 3 + 1];
    s[2][t] = qp[n * 3 + 2];
    __syncthreads();
    for (int off = 128; off > 0; off >>= 1) {
        if (t < off) {
            s[0][t] += s[0][t + off];
            s[1][t] += s[1][t + off];
            s[2][t] += s[2][t + off];
        }
        __syncthreads();
    }
    if (t == 0) {
        partial[blockIdx.x * 4 + 0] = s[0][0];
        partial[blockIdx.x * 4 + 1] = s[1][0];
        partial[blockIdx.x * 4 + 2] = s[2][0];
    }
}

__global__ __launch_bounds__(256) void k_final(const float* __restrict__ partial,
                                               float* __restrict__ mean) {
    __shared__ float s[3][256];
    int t = threadIdx.x;
    s[0][t] = partial[t * 4 + 0];
    s[1][t] = partial[t * 4 + 1];
    s[2][t] = partial[t * 4 + 2];
    __syncthreads();
    for (int off = 128; off > 0; off >>= 1) {
        if (t < off) {
            s[0][t] += s[0][t + off];
            s[1][t] += s[1][t + off];
            s[2][t] += s[2][t + off];
        }
        __syncthreads();
    }
    if (t < 3) mean[t] = s[t][0] * (1.0f / 65536.0f);
}

// ---------------- prep 1: fp16-convert the pid feature slices -------------
// dst layout: F16[p][jimg][128*128*8] fp16 -> texel = 16B (one dwordx4).
__global__ __launch_bounds__(256) void k_prep_feat(
    const float* __restrict__ featx, const float* __restrict__ featy,
    const float* __restrict__ featz, const int* __restrict__ idp,
    _Float16* __restrict__ F16) {
    int flat = blockIdx.x * 256 + threadIdx.x;     // 1,179,648 threads
    int g = flat >> 14;                            // image 0..71 (p*24+jimg)
    int r = flat & 16383;                          // texel-half-group within image
    int p = g / 24;
    int jimg = g - p * 24;
    const float* feat = (p == 0) ? featx : (p == 1) ? featy : featz;
    int pid = *idp;
    const float* src = feat + ((size_t)jimg * PP + (size_t)pid) * 131072 + (size_t)r * 8;
    float4 a = *(const float4*)src;
    float4 b = *(const float4*)(src + 4);
    h8 o;
    o[0] = (_Float16)a.x; o[1] = (_Float16)a.y;
    o[2] = (_Float16)a.z; o[3] = (_Float16)a.w;
    o[4] = (_Float16)b.x; o[5] = (_Float16)b.y;
    o[6] = (_Float16)b.z; o[7] = (_Float16)b.w;
    *(h8*)(F16 + (size_t)flat * 8) = o;
}

// ---------------- prep 2: packed per-(plane,point) sample coords ----------
// entry: uint2 { x0 | y0<<8 | x1<<16 | y1<<24 , half2(fx,fy) }  (8B)
__global__ __launch_bounds__(256) void k_prep_coord(
    const float* __restrict__ qp, const float* __restrict__ scale,
    const float* __restrict__ mean, uint2* __restrict__ coords) {
    int n = blockIdx.x * 256 + threadIdx.x;
    float q0 = qp[n * 3 + 0], q1 = qp[n * 3 + 1], q2 = qp[n * 3 + 2];
    float qv[3] = {q0, q1, q2};
#pragma unroll
    for (int p = 0; p < 3; ++p) {
        int wc = (p + 1) - ((p + 1) >= 3 ? 3 : 0);   // (p+1)%3
        int hc = p;
        float gw = (qv[wc] - mean[wc]) * (2.0f / scale[wc]);
        float gh = (qv[hc] - mean[hc]) * (2.0f / scale[hc]);
        float ixf = (gw + 1.0f) * 63.5f;
        float iyf = (gh + 1.0f) * 63.5f;
        float ix0 = floorf(ixf);
        float iy0 = floorf(iyf);
        float fx = ixf - ix0;
        float fy = iyf - iy0;
        int x0i = (int)ix0, y0i = (int)iy0;
        int x0 = min(127, max(0, x0i));
        int x1 = min(127, max(0, x0i + 1));
        int y0 = min(127, max(0, y0i));
        int y1 = min(127, max(0, y0i + 1));
        unsigned lo = (unsigned)x0 | ((unsigned)y0 << 8) |
                      ((unsigned)x1 << 16) | ((unsigned)y1 << 24);
        h2 f; f[0] = (_Float16)fx; f[1] = (_Float16)fy;
        uint2 e;
        e.x = lo;
        e.y = __builtin_bit_cast(unsigned, f);
        coords[(size_t)p * 65536 + (size_t)n] = e;
    }
}

// ---------------- stage 1: fp16-texel sampling, packed lerp ---------------
// One lane per point; texel = 16B fp16 (all 8 channels) -> 4 dwordx4 taps.
// LDS transpose turns 8x2B scattered stores into one dwordx4 per thread.
__global__ __launch_bounds__(256) void k_sample(
    const _Float16* __restrict__ F16, const uint2* __restrict__ coords,
    _Float16* __restrict__ T) {
    // grid = 72 groups * 256 chunks = 18432 blocks; 2304 per XCD (chunked)
    int b = blockIdx.x;
    int Lid = (b & 7) * 2304 + (b >> 3);
    int group = Lid >> 8;                  // p*24 + jimg
    int chunk = Lid & 255;
    int p = group / 24;
    int jimg = group - p * 24;
    int t = threadIdx.x;
    int n0 = chunk << 8;
    int n = n0 + t;

    uint2 pc = coords[(size_t)p * 65536 + (size_t)n];
    int x0 = pc.x & 255;
    int y0 = (pc.x >> 8) & 255;
    int x1 = (pc.x >> 16) & 255;
    int y1 = pc.x >> 24;
    h2 f = __builtin_bit_cast(h2, pc.y);
    _Float16 fx = f[0], fy = f[1];
    _Float16 ox = (_Float16)1.0f - fx;
    _Float16 oy = (_Float16)1.0f - fy;
    _Float16 w00 = ox * oy, w01 = fx * oy, w10 = ox * fy, w11 = fx * fy;

    const h8* img = (const h8*)(F16 + (size_t)group * 131072);
    h8 A = img[y0 * LL + x0];
    h8 B = img[y0 * LL + x1];
    h8 C = img[y1 * LL + x0];
    h8 D = img[y1 * LL + x1];

    h8 R = A * w00 + B * w01 + C * w10 + D * w11;

    __shared__ _Float16 sbuf[8 * 256];
#pragma unroll
    for (int c = 0; c < 8; ++c) sbuf[c * 256 + t] = R[c];
    __syncthreads();

    int c = t >> 5;              // channel strip this thread stores
    int g = t & 31;              // 8-point group within the strip
    h8 outv = *(const h8*)&sbuf[c * 256 + g * 8];
    size_t base = (size_t)p * TPL + ((size_t)(jimg * 8 + c) << 16) +
                  (size_t)(n0 + g * 8);
    *(h8*)(T + base) = outv;
}

// ---------------- stage 2: coalesced weighted reduction (fp16 in) --------
__global__ __launch_bounds__(256) void k_combine(
    const _Float16* __restrict__ T, const float* __restrict__ sw,
    float* __restrict__ out) {
    int t = blockIdx.x * 256 + threadIdx.x;   // [0, 3*65536)
    int p = t >> 16;
    int np = t & 65535;
    const _Float16* Tp = T + (size_t)p * TPL + (size_t)np * 192;
    const float* swp = sw + (size_t)np * JJ;

    float w[24];
#pragma unroll
    for (int q = 0; q < 6; ++q) {
        float4 wv = *(const float4*)(swp + q * 4);
        w[q * 4 + 0] = wv.x;
        w[q * 4 + 1] = wv.y;
        w[q * 4 + 2] = wv.z;
        w[q * 4 + 3] = wv.w;
    }

    float acc[8] = {0, 0, 0, 0, 0, 0, 0, 0};
#pragma unroll
    for (int j = 0; j < JJ; ++j) {
        h8 u = *(const h8*)(Tp + j * 8);
        float wj = w[j];
#pragma unroll
        for (int ci = 0; ci < 8; ++ci) acc[ci] += wj * (float)u[ci];
    }
    float4* o = (float4*)(out + (size_t)np * OUTC + p * 8);
    o[0] = make_float4(acc[0], acc[1], acc[2], acc[3]);
    o[1] = make_float4(acc[4], acc[5], acc[6], acc[7]);
}

// ---------------- fallback (round-1 kernel) if ws too small ----------------
__global__ __launch_bounds__(256) void k_main(
    const float* __restrict__ featx, const float* __restrict__ featy,
    const float* __restrict__ featz, const float* __restrict__ qp,
    const float* __restrict__ scale, const float* __restrict__ sw,
    const int* __restrict__ idp, const float* __restrict__ mean,
    float* __restrict__ out) {
    int t = blockIdx.x * 256 + threadIdx.x;
    if (t >= TOTAL) return;
    int np = t / OUTC;
    int cp = t - np * OUTC;
    int p  = cp >> 3;
    int c  = cp & 7;

    const float* feat = (p == 0) ? featx : (p == 1) ? featy : featz;
    int pid = *idp;
    int wc = (p + 1) - ((p + 1) >= 3 ? 3 : 0);
    int hc = p;
    float mw = mean[wc], mh = mean[hc];
    float invw = 2.0f / scale[wc];
    float invh = 2.0f / scale[hc];

    const float* featpid = feat + (size_t)pid * (LL * LL * CC);
    int ibase = np * 192 + c;
    float acc = 0.0f;

#pragma unroll 4
    for (int j = 0; j < JJ; ++j) {
        int i  = ibase + j * 8;
        int jc = i >> 16;
        int n  = i & 65535;
        int jimg = jc >> 3;
        int cimg = jc & 7;
        const float* img = featpid + (size_t)jimg * (PP * LL * LL * CC) + cimg;

        float gw = (qp[n * 3 + wc] - mw) * invw;
        float gh = (qp[n * 3 + hc] - mh) * invh;
        float ixf = (gw + 1.0f) * 63.5f;
        float iyf = (gh + 1.0f) * 63.5f;
        float ix0 = floorf(ixf);
        float iy0 = floorf(iyf);
        float fx = ixf - ix0;
        float fy = iyf - iy0;
        int x0i = (int)ix0;
        int y0i = (int)iy0;
        int x0 = min(127, max(0, x0i));
        int x1 = min(127, max(0, x0i + 1));
        int y0 = min(127, max(0, y0i));
        int y1 = min(127, max(0, y0i + 1));

        int r0 = y0 * (LL * CC);
        int r1 = y1 * (LL * CC);
        float v00 = img[r0 + x0 * CC];
        float v01 = img[r0 + x1 * CC];
        float v10 = img[r1 + x0 * CC];
        float v11 = img[r1 + x1 * CC];

        float omfx = 1.0f - fx;
        float omfy = 1.0f - fy;
        float S = omfx * omfy * v00 + fx * omfy * v01 +
                  omfx * fy * v10 + fx * fy * v11;
        acc += sw[np * JJ + j] * S;
    }
    out[t] = acc;
}

extern "C" void kernel_launch(void* const* d_in, const int* in_sizes, int n_in,
                              void* d_out, int out_size, void* d_ws, size_t ws_size,
                              hipStream_t stream) {
    const float* featx = (const float*)d_in[0];
    const float* featy = (const float*)d_in[1];
    const float* featz = (const float*)d_in[2];
    const float* qp    = (const float*)d_in[3];
    const float* scale = (const float*)d_in[4];
    const float* sw    = (const float*)d_in[5];
    const int*   idp   = (const int*)d_in[6];
    float* out = (float*)d_out;

    // ws layout (bytes): T | F16 | coords | partial | mean
    size_t off_T = 0;
    size_t off_F = off_T + TSZ * sizeof(_Float16);          // 75,497,472
    size_t off_C = off_F + FSZ * sizeof(_Float16);          // +18,874,368
    size_t off_P = off_C + CSZ * sizeof(uint2);             // +1,572,864
    size_t off_M = off_P + 1024 * sizeof(float);
    size_t needed = off_M + 4 * sizeof(float);

    if (ws_size >= needed) {
        char* wsb = (char*)d_ws;
        _Float16* T    = (_Float16*)(wsb + off_T);
        _Float16* F16  = (_Float16*)(wsb + off_F);
        uint2* coords  = (uint2*)(wsb + off_C);
        float* partial = (float*)(wsb + off_P);
        float* mean    = (float*)(wsb + off_M);

        k_partial<<<256, 256, 0, stream>>>(qp, partial);
        k_final<<<1, 256, 0, stream>>>(partial, mean);
        k_prep_feat<<<4608, 256, 0, stream>>>(featx, featy, featz, idp, F16);
        k_prep_coord<<<256, 256, 0, stream>>>(qp, scale, mean, coords);
        k_sample<<<72 * 256, 256, 0, stream>>>(F16, coords, T);
        k_combine<<<3 * 65536 / 256, 256, 0, stream>>>(T, sw, out);
    } else {
        float* ws = (float*)d_ws;
        float* mean    = ws;
        float* partial = ws + 4;
        k_partial<<<256, 256, 0, stream>>>(qp, partial);
        k_final<<<1, 256, 0, stream>>>(partial, mean);
        k_main<<<(TOTAL + 255) / 256, 256, 0, stream>>>(
            featx, featy, featz, qp, scale, sw, idp, mean, out);
    }
}

// Round 5
// 69.493 us; speedup vs baseline: 7.9303x; 1.2890x over previous
//
#include <hip/hip_runtime.h>

// Problem constants
constexpr int NPQ = 65536;  // N query points
constexpr int JJ = 24, CC = 8, PP = 8, LL = 128;
constexpr int OUTC = 24;
constexpr int TOTAL = NPQ * OUTC;
constexpr int NCHP = 192;                    // channels per plane (J*C)
constexpr size_t PLANE_W = 16384;            // u32 words per channel-plane (64KB)
constexpr size_t FC_WORDS = (size_t)576 * PLANE_W;   // 3 planes * 192 ch

typedef _Float16 h2 __attribute__((ext_vector_type(2)));

// ---------------- mean reduction (deterministic, 2-stage) ----------------

__global__ __launch_bounds__(256) void k_partial(const float* __restrict__ qp,
                                                 float* __restrict__ partial) {
    __shared__ float s[3][256];
    int t = threadIdx.x;
    int n = blockIdx.x * 256 + t;
    s[0][t] = qp[n * 3 + 0];
    s[1][t] = qp[n * 3 + 1];
    s[2][t] = qp[n * 3 + 2];
    __syncthreads();
    for (int off = 128; off > 0; off >>= 1) {
        if (t < off) {
            s[0][t] += s[0][t + off];
            s[1][t] += s[1][t + off];
            s[2][t] += s[2][t + off];
        }
        __syncthreads();
    }
    if (t == 0) {
        partial[blockIdx.x * 4 + 0] = s[0][0];
        partial[blockIdx.x * 4 + 1] = s[1][0];
        partial[blockIdx.x * 4 + 2] = s[2][0];
    }
}

__global__ __launch_bounds__(256) void k_final(const float* __restrict__ partial,
                                               float* __restrict__ mean) {
    __shared__ float s[3][256];
    int t = threadIdx.x;
    s[0][t] = partial[t * 4 + 0];
    s[1][t] = partial[t * 4 + 1];
    s[2][t] = partial[t * 4 + 2];
    __syncthreads();
    for (int off = 128; off > 0; off >>= 1) {
        if (t < off) {
            s[0][t] += s[0][t + off];
            s[1][t] += s[1][t + off];
            s[2][t] += s[2][t + off];
        }
        __syncthreads();
    }
    if (t < 3) mean[t] = s[t][0] * (1.0f / 65536.0f);
}

// -------- prep 1: channel-major fp16 planes, x-pair duplicated -----------
// FcW[plane][y*128+x] = u32( fp16 tex[y][x], fp16 tex[y][min(x+1,127)] )
// plane index = p*192 + jimg*8 + c. Every bilinear x-pair (xr, xr+1),
// xr<=126, is ONE aligned 4B word -> one ds_read_b32 in the fused kernel.
__global__ __launch_bounds__(256) void k_prep_feat(
    const float* __restrict__ fx_, const float* __restrict__ fy_,
    const float* __restrict__ fz_, const int* __restrict__ idp,
    unsigned int* __restrict__ FcW) {
    int bid = blockIdx.x;          // 72 images * 64 row-pairs = 4608
    int g = bid >> 6;              // image 0..71  (p*24 + jimg)
    int rg = bid & 63;
    int p = g / 24, jimg = g - p * 24;
    const float* feat = (p == 0) ? fx_ : (p == 1) ? fy_ : fz_;
    int pid = *idp;
    int t = threadIdx.x;
    int ly = t >> 7, x = t & 127;
    int y = rg * 2 + ly;
    const float* src = feat + (((size_t)jimg * PP + (size_t)pid) * 16384 +
                               (size_t)(y * 128 + x)) * 8;
    float4 a = *(const float4*)src;
    float4 b = *(const float4*)(src + 4);
    __shared__ _Float16 sh[2][128][8];
    sh[ly][x][0] = (_Float16)a.x;
    sh[ly][x][1] = (_Float16)a.y;
    sh[ly][x][2] = (_Float16)a.z;
    sh[ly][x][3] = (_Float16)a.w;
    sh[ly][x][4] = (_Float16)b.x;
    sh[ly][x][5] = (_Float16)b.y;
    sh[ly][x][6] = (_Float16)b.z;
    sh[ly][x][7] = (_Float16)b.w;
    __syncthreads();
    int xn = (x < 127) ? x + 1 : 127;
#pragma unroll
    for (int c = 0; c < 8; ++c) {
        h2 w;
        w[0] = sh[ly][x][c];
        w[1] = sh[ly][xn][c];
        FcW[((size_t)g * 8 + c) * PLANE_W + (size_t)(y * 128 + x)] =
            __builtin_bit_cast(unsigned int, w);
    }
}

// -------- prep 2: per-(plane,point) sample descriptor (16B) --------------
// { off0 | off1<<16 (byte offsets into the word-plane, rows y0r/y1r at xr),
//   h2(w00,w01), h2(w10,w11), 0 }  with clamp-adjusted x-pair weights.
__global__ __launch_bounds__(256) void k_prep_coord(
    const float* __restrict__ qp, const float* __restrict__ scale,
    const float* __restrict__ mean, uint4* __restrict__ co) {
    int n = blockIdx.x * 256 + threadIdx.x;
    float qv[3] = {qp[n * 3 + 0], qp[n * 3 + 1], qp[n * 3 + 2]};
#pragma unroll
    for (int p = 0; p < 3; ++p) {
        int wc = (p + 1) - ((p + 1) >= 3 ? 3 : 0);   // (p+1)%3
        int hc = p;
        float gw = (qv[wc] - mean[wc]) * (2.0f / scale[wc]);
        float gh = (qv[hc] - mean[hc]) * (2.0f / scale[hc]);
        float ixf = (gw + 1.0f) * 63.5f;
        float iyf = (gh + 1.0f) * 63.5f;
        float fx0 = floorf(ixf), fy0 = floorf(iyf);
        float fx = ixf - fx0, fy = iyf - fy0;
        int x0i = (int)fx0, y0i = (int)fy0;
        int y0r = min(127, max(0, y0i));
        int y1r = min(127, max(0, y0i + 1));
        int xr = min(126, max(0, x0i));
        // x weights on the pair (xr, xr+1); clamp folds all weight to the
        // surviving texel (weights always sum to 1, matching the reference's
        // independent index clamping with unclamped weights).
        float wl = 1.0f - fx, wh = fx;
        if (x0i < 0)   { wl = 1.0f; wh = 0.0f; }
        if (x0i > 126) { wl = 0.0f; wh = 1.0f; }
        float oy = 1.0f - fy;
        h2 w01, w23;
        w01[0] = (_Float16)(wl * oy);
        w01[1] = (_Float16)(wh * oy);
        w23[0] = (_Float16)(wl * fy);
        w23[1] = (_Float16)(wh * fy);
        unsigned off0 = (unsigned)(y0r * 128 + xr) * 4u;
        unsigned off1 = (unsigned)(y1r * 128 + xr) * 4u;
        uint4 e;
        e.x = off0 | (off1 << 16);
        e.y = __builtin_bit_cast(unsigned int, w01);
        e.z = __builtin_bit_cast(unsigned int, w23);
        e.w = 0u;
        co[((size_t)p << 16) + (size_t)n] = e;
    }
}

// -------- fused sample+combine ------------------------------------------
// Block = (plane p, channel jc, np-half). Channel-plane (64KB) in LDS.
// Thread owns outputs (np,c); 24 j-samples each: 1 coord dwordx4 +
// 2 ds_read_b32 + pk-fp16 lerp, accumulated in a register. Boundary nps
// (192-window straddling a 65536 multiple) go to pre/post partial buffers.
__device__ __forceinline__ float sample1(const unsigned int* splane, uint4 d) {
    unsigned off0 = d.x & 0xffffu, off1 = d.x >> 16;
    h2 w01 = __builtin_bit_cast(h2, d.y);
    h2 w23 = __builtin_bit_cast(h2, d.z);
    h2 p0 = *(const h2*)((const char*)splane + off0);
    h2 p1 = *(const h2*)((const char*)splane + off1);
    h2 tt = p0 * w01 + p1 * w23;
    return (float)tt[0] + (float)tt[1];
}

__global__ __launch_bounds__(512, 4) void k_fused(
    const unsigned int* __restrict__ FcW, const uint4* __restrict__ co,
    const float* __restrict__ sw, float* __restrict__ out,
    float* __restrict__ preb, float* __restrict__ postb) {
    int bid = blockIdx.x;          // 1152 = 576 (p,jc) * 2 halves
    int half = bid & 1;
    int jcp = bid >> 1;            // p*192 + jc
    int p = jcp / NCHP;
    int jc = jcp - p * NCHP;

    __shared__ unsigned int splane[16384];   // 64KB
    {
        const uint4* src = (const uint4*)(FcW + (size_t)jcp * PLANE_W);
        uint4* dst = (uint4*)splane;
#pragma unroll
        for (int q = 0; q < 8; ++q)
            dst[q * 512 + threadIdx.x] = src[q * 512 + threadIdx.x];
    }
    __syncthreads();

    int i0 = jc << 16;
    int r  = (jc % 3) * 64;            // i0 % 192
    int i1 = (jc + 1) << 16;
    int r1 = ((jc + 1) % 3) * 64;      // i1 % 192
    int npF_lo = (i0 + 191) / 192;     // first fully-covered output row
    int npF_hi = i1 / 192;             // exclusive end of full rows
    int cnt = npF_hi - npF_lo;
    int mid = npF_lo + (cnt >> 1);
    int loR = half ? mid : npF_lo;
    int hiR = half ? npF_hi : mid;
    bool hasPre  = (half == 0) && (r != 0);
    bool hasPost = (half == 1) && (r1 != 0);

    int nFull = (hiR - loR) * 8;
    int nTot = nFull + (hasPre ? 8 : 0) + (hasPost ? 8 : 0);
    const uint4* cop = co + ((size_t)p << 16);

    for (int k = threadIdx.x; k < nTot; k += 512) {
        if (k < nFull) {
            int np = loR + (k >> 3);
            int c = k & 7;
            const uint4* cb = cop + (np * 192 + c - i0);
            const float4* swv = (const float4*)(sw + (size_t)np * 24);
            float4 s0 = swv[0], s1 = swv[1], s2 = swv[2];
            float4 s3 = swv[3], s4 = swv[4], s5 = swv[5];
            float swreg[24] = {s0.x, s0.y, s0.z, s0.w, s1.x, s1.y, s1.z, s1.w,
                               s2.x, s2.y, s2.z, s2.w, s3.x, s3.y, s3.z, s3.w,
                               s4.x, s4.y, s4.z, s4.w, s5.x, s5.y, s5.z, s5.w};
            float acc = 0.0f;
#pragma unroll
            for (int j = 0; j < 24; ++j) {
                uint4 d = cb[j * 8];
                acc += swreg[j] * sample1(splane, d);
            }
            out[(size_t)np * 24 + p * 8 + c] = acc;
        } else {
            bool isPre = hasPre && (k < nFull + 8);
            int c = (k - nFull) & 7;
            int np = isPre ? (i0 / 192) : npF_hi;
            int jlo = isPre ? (r >> 3) : 0;
            int jhi = isPre ? 24 : (r1 >> 3);
            int n0 = np * 192 + c - i0;    // may be negative; n0+8*jlo >= 0
            float acc = 0.0f;
            for (int j = jlo; j < jhi; ++j) {
                uint4 d = cop[n0 + j * 8];
                acc += sw[(size_t)np * 24 + j] * sample1(splane, d);
            }
            float* dst = isPre ? preb : postb;
            dst[(size_t)jcp * 8 + c] = acc;
        }
    }
}

// -------- fixup: sum the two partial halves of boundary rows -------------
__global__ __launch_bounds__(256) void k_fix(const float* __restrict__ preb,
                                             const float* __restrict__ postb,
                                             float* __restrict__ out) {
    int t = blockIdx.x * 256 + threadIdx.x;   // over 3*191*8
    if (t >= 3 * 191 * 8) return;
    int c = t & 7;
    int rest = t >> 3;
    int jc = rest % 191;
    int p = rest / 191;
    if (((jc + 1) % 3) == 0) return;          // no straddle at this boundary
    int np = ((jc + 1) << 16) / 192;
    out[(size_t)np * 24 + p * 8 + c] =
        postb[((size_t)p * NCHP + jc) * 8 + c] +
        preb[((size_t)p * NCHP + jc + 1) * 8 + c];
}

// ---------------- fallback (round-1 kernel) if ws too small ---------------
__global__ __launch_bounds__(256) void k_main(
    const float* __restrict__ featx, const float* __restrict__ featy,
    const float* __restrict__ featz, const float* __restrict__ qp,
    const float* __restrict__ scale, const float* __restrict__ sw,
    const int* __restrict__ idp, const float* __restrict__ mean,
    float* __restrict__ out) {
    int t = blockIdx.x * 256 + threadIdx.x;
    if (t >= TOTAL) return;
    int np = t / OUTC;
    int cp = t - np * OUTC;
    int p  = cp >> 3;
    int c  = cp & 7;
    const float* feat = (p == 0) ? featx : (p == 1) ? featy : featz;
    int pid = *idp;
    int wc = (p + 1) - ((p + 1) >= 3 ? 3 : 0);
    int hc = p;
    float mw = mean[wc], mh = mean[hc];
    float invw = 2.0f / scale[wc];
    float invh = 2.0f / scale[hc];
    const float* featpid = feat + (size_t)pid * (LL * LL * CC);
    int ibase = np * 192 + c;
    float acc = 0.0f;
#pragma unroll 4
    for (int j = 0; j < JJ; ++j) {
        int i  = ibase + j * 8;
        int jc = i >> 16;
        int n  = i & 65535;
        int jimg = jc >> 3;
        int cimg = jc & 7;
        const float* img = featpid + (size_t)jimg * (PP * LL * LL * CC) + cimg;
        float gw = (qp[n * 3 + wc] - mw) * invw;
        float gh = (qp[n * 3 + hc] - mh) * invh;
        float ixf = (gw + 1.0f) * 63.5f;
        float iyf = (gh + 1.0f) * 63.5f;
        float ix0 = floorf(ixf), iy0 = floorf(iyf);
        float fx = ixf - ix0, fy = iyf - iy0;
        int x0i = (int)ix0, y0i = (int)iy0;
        int x0 = min(127, max(0, x0i));
        int x1 = min(127, max(0, x0i + 1));
        int y0 = min(127, max(0, y0i));
        int y1 = min(127, max(0, y0i + 1));
        int r0 = y0 * (LL * CC);
        int r1 = y1 * (LL * CC);
        float v00 = img[r0 + x0 * CC];
        float v01 = img[r0 + x1 * CC];
        float v10 = img[r1 + x0 * CC];
        float v11 = img[r1 + x1 * CC];
        float omfx = 1.0f - fx, omfy = 1.0f - fy;
        float S = omfx * omfy * v00 + fx * omfy * v01 +
                  omfx * fy * v10 + fx * fy * v11;
        acc += sw[np * JJ + j] * S;
    }
    out[t] = acc;
}

extern "C" void kernel_launch(void* const* d_in, const int* in_sizes, int n_in,
                              void* d_out, int out_size, void* d_ws, size_t ws_size,
                              hipStream_t stream) {
    const float* featx = (const float*)d_in[0];
    const float* featy = (const float*)d_in[1];
    const float* featz = (const float*)d_in[2];
    const float* qp    = (const float*)d_in[3];
    const float* scale = (const float*)d_in[4];
    const float* sw    = (const float*)d_in[5];
    const int*   idp   = (const int*)d_in[6];
    float* out = (float*)d_out;

    // ws layout (bytes)
    size_t off_Fc = 0;
    size_t off_co = off_Fc + FC_WORDS * 4;                 // 37,748,736
    size_t off_pre = off_co + (size_t)3 * 65536 * 16;      // +3,145,728
    size_t off_post = off_pre + 576 * 8 * 4;
    size_t off_partial = off_post + 576 * 8 * 4;
    size_t off_mean = off_partial + 4096;
    size_t needed = off_mean + 16;

    if (ws_size >= needed) {
        char* wsb = (char*)d_ws;
        unsigned int* FcW = (unsigned int*)(wsb + off_Fc);
        uint4* co        = (uint4*)(wsb + off_co);
        float* preb      = (float*)(wsb + off_pre);
        float* postb     = (float*)(wsb + off_post);
        float* partial   = (float*)(wsb + off_partial);
        float* mean      = (float*)(wsb + off_mean);

        k_partial<<<256, 256, 0, stream>>>(qp, partial);
        k_final<<<1, 256, 0, stream>>>(partial, mean);
        k_prep_feat<<<4608, 256, 0, stream>>>(featx, featy, featz, idp, FcW);
        k_prep_coord<<<256, 256, 0, stream>>>(qp, scale, mean, co);
        k_fused<<<1152, 512, 0, stream>>>(FcW, co, sw, out, preb, postb);
        k_fix<<<18, 256, 0, stream>>>(preb, postb, out);
    } else {
        float* ws = (float*)d_ws;
        float* mean    = ws;
        float* partial = ws + 4;
        k_partial<<<256, 256, 0, stream>>>(qp, partial);
        k_final<<<1, 256, 0, stream>>>(partial, mean);
        k_main<<<(TOTAL + 255) / 256, 256, 0, stream>>>(
            featx, featy, featz, qp, scale, sw, idp, mean, out);
    }
}